// Round 25
// baseline (177.623 us; speedup 1.0000x reference)
//
#include <hip/hip_runtime.h>
#include <math.h>

#define N_ATOMS 4096
#define N_EDGES 131072
#define PI6 0.52359877559829887f
#define CAP 128

typedef __attribute__((ext_vector_type(8))) short bf16x8;
typedef __attribute__((ext_vector_type(4))) float f32x4;

#define MFMA(A,B,C) __builtin_amdgcn_mfma_f32_16x16x32_bf16((A),(B),(C),0,0,0)

__device__ __forceinline__ float silu_f(float x){ return x / (1.f + __expf(-x)); }
__device__ __forceinline__ float sigmoid_f(float x){ return 1.f / (1.f + __expf(-x)); }
__device__ __forceinline__ unsigned int f2bf(float f){
  unsigned int u = __float_as_uint(f);
  return (u + 0x7FFFu + ((u>>16)&1u)) >> 16;
}
__device__ __forceinline__ float bf2f(unsigned short h){
  return __uint_as_float(((unsigned int)h)<<16);
}
__device__ __forceinline__ bf16x8 ld8(const unsigned short* p){
  union { unsigned int u[4]; bf16x8 v; } r;
  const unsigned int* q = (const unsigned int*)p;
  r.u[0]=q[0]; r.u[1]=q[1]; r.u[2]=q[2]; r.u[3]=q[3];
  return r.v;
}
__device__ __forceinline__ void split_store(float v, unsigned short* ph, unsigned short* pl){
  unsigned int hb = f2bf(v);
  *ph = (unsigned short)hb;
  *pl = (unsigned short)f2bf(v - __uint_as_float(hb<<16));
}

// ---------- prep: weight planes + zero bucket cursor ----------
__global__ __launch_bounds__(256) void prep_kernel(
  const float* __restrict__ attn_w_out, const float* __restrict__ rad_w2,
  const float* __restrict__ tp_w, const float* __restrict__ msg_w1,
  const float* __restrict__ msg_w2, const float* __restrict__ attn_w_in,
  const float* __restrict__ gate_w, const float* __restrict__ out_w,
  int* __restrict__ cursor,
  unsigned short* __restrict__ w2t_h, unsigned short* __restrict__ w2t_l,
  unsigned short* __restrict__ tpwT_h, unsigned short* __restrict__ tpwT_l,
  unsigned short* __restrict__ w1T_h, unsigned short* __restrict__ w1T_l,
  unsigned short* __restrict__ w2T_h, unsigned short* __restrict__ w2T_l,
  unsigned short* __restrict__ awin_h, unsigned short* __restrict__ awin_l,
  unsigned short* __restrict__ gwT_h, unsigned short* __restrict__ gwT_l,
  unsigned short* __restrict__ awo_h, unsigned short* __restrict__ awo_l,
  unsigned short* __restrict__ owT_h, unsigned short* __restrict__ owT_l)
{
  int idx = blockIdx.x*256 + threadIdx.x;
  if (idx < 4096) cursor[idx] = 0;
  if (idx < 8192){                        // w2t: rad_w2^T hi/lo [128][64]
    int j = idx; int k = j>>7, c = j&127;
    split_store(rad_w2[k*128+c], &w2t_h[c*64+k], &w2t_l[c*64+k]);
  } else if (idx < 155648){               // tpwT: [128 col][1152 k] reordered
    int j = idx - 8192; int col = j&127, kk = j>>7;
    int jj = kk>>7, c = kk&127;
    int r = (jj==0)? c : (jj<4 ? 128 + c*3 + (jj-1) : 512 + c*5 + (jj-4));
    split_store(tp_w[r*128+col], &tpwT_h[col*1152+kk], &tpwT_l[col*1152+kk]);
  } else if (idx < 180224){               // w1T: [128][192]
    int j = idx - 155648; int col = j&127, k = j>>7;
    split_store(msg_w1[k*128+col], &w1T_h[col*192+k], &w1T_l[col*192+k]);
  } else if (idx < 196608){               // w2T: [128][128]
    int j = idx - 180224; int col = j&127, k = j>>7;
    split_store(msg_w2[k*128+col], &w2T_h[col*128+k], &w2T_l[col*128+k]);
  } else if (idx < 245760){               // awin: attn_w_in [384][128] as-is
    int j = idx - 196608;
    split_store(attn_w_in[j], &awin_h[j], &awin_l[j]);
  } else if (idx < 262144){               // gwT: gate_w^T [col][k]
    int j = idx - 245760; int col = j&127, k = j>>7;
    split_store(gate_w[k*128+col], &gwT_h[col*128+k], &gwT_l[col*128+k]);
  } else if (idx < 278528){               // awo: attn_w_out as-is [o][k]
    int j = idx - 262144;
    split_store(attn_w_out[j], &awo_h[j], &awo_l[j]);
  } else if (idx < 294912){               // owT: out_w^T [col][k]
    int j = idx - 278528; int col = j&127, k = j>>7;
    split_store(out_w[k*128+col], &owT_h[col*128+k], &owT_l[col*128+k]);
  }
}

// ---------- bucket: per-atom edge lists via atomics ----------
__global__ __launch_bounds__(256) void bucket_kernel(
  const int* __restrict__ edge_index, int* __restrict__ cursor, int* __restrict__ edge_slot)
{
  int e = blockIdx.x*256 + threadIdx.x;
  if (e < N_EDGES){
    int d = edge_index[N_EDGES + e];
    int pos = atomicAdd(&cursor[d], 1);
    if (pos < CAP) edge_slot[d*CAP + pos] = e;
  }
}

// ---------- edge features: all-MFMA, 2 atoms/block, fused C+D ----------
// RB staging and R2w scratch ALIAS one LDS pool (disjoint live ranges):
// LDS 43 -> 38.1 KB => 4 blocks/CU (32 waves, HW max). RB's zero K-padding
// (cols 8..31) is re-written every chunk in phase A since R2w clobbers it.
__global__ __launch_bounds__(512) void edge_F_kernel(
  const float* __restrict__ edge_vectors, const float* __restrict__ edge_lengths,
  const float* __restrict__ rad_w1, const float* __restrict__ rad_b1,
  const unsigned short* __restrict__ w2t_h, const unsigned short* __restrict__ w2t_l,
  const float* __restrict__ rad_b2,
  const int* __restrict__ cursor, const int* __restrict__ edge_slot,
  unsigned short* __restrict__ Fh, unsigned short* __restrict__ Fl)
{
  const int tid = threadIdx.x;
  const int w = tid >> 6, lane = tid & 63;
  const int l15 = lane & 15, lg = lane >> 4;
  const int wm = w >> 2, wn2 = w & 3;

  __shared__ unsigned short W1h[64][36],  W1l[64][36];   // 9.2 KB
  __shared__ unsigned short SHh[16][36],  SHl[16][36];   // 2.3 KB
  __shared__ unsigned short R1h[32][72],  R1l[32][72];   // 9.2 KB
  __shared__ __align__(16) unsigned short pool[8704];    // 17.4 KB: RB | R2w union

  unsigned short (*RBh)[36] = (unsigned short(*)[36]) pool;           // 32x36
  unsigned short (*RBl)[36] = (unsigned short(*)[36])(pool + 1152);   // 32x36
  unsigned short (*R2wh)[16][34] = (unsigned short(*)[16][34]) pool;          // 8x16x34
  unsigned short (*R2wl)[16][34] = (unsigned short(*)[16][34])(pool + 4352);  // 8x16x34

  bf16x8 WAh[2], WAl[2];
  {
    int c = w*16 + l15;
    WAh[0] = ld8(&w2t_h[c*64 + lg*8]);
    WAh[1] = ld8(&w2t_h[c*64 + 32 + lg*8]);
    WAl[0] = ld8(&w2t_l[c*64 + lg*8]);
    WAl[1] = ld8(&w2t_l[c*64 + 32 + lg*8]);
  }

  for (int i = tid; i < 2048; i += 512){
    int c = i >> 5, k = i & 31;
    float v = (k < 8) ? rad_w1[k*64 + c] : 0.f;
    split_store(v, &W1h[c][k], &W1l[c][k]);
  }
  for (int i = tid; i < 8704; i += 512) pool[i] = 0;
  for (int i = tid; i < 16*36; i += 512){ SHh[i/36][i%36]=0; SHl[i/36][i%36]=0; }

  const float b1v = rad_b1[wn2*16 + l15];
  float b2r[4];
  #pragma unroll
  for (int r=0;r<4;r++) b2r[r] = rad_b2[w*16 + lg*4 + r];

  __syncthreads();

  for (int aa = 0; aa < 2; ++aa){
    const int a = blockIdx.x*2 + aa;
    const int deg = min(cursor[a], CAP);
    const int base = a*CAP;
    f32x4 facc = {0.f,0.f,0.f,0.f};

    for (int t0 = 0; t0 < deg; t0 += 32){
      if (tid < 256){
        int e8 = tid >> 3, k = tid & 7;
        int idx = t0 + e8;
        int eid = edge_slot[base + (idx < deg ? idx : 0)];
        float d = edge_lengths[eid];
        float cut = 0.5f*(__cosf(d*PI6)+1.f)*(d<6.f?1.f:0.f);
        float rb = __sinf(d*((float)(k+1)*PI6))/d*cut;
        if (idx >= deg) rb = 0.f;
        split_store(rb, &RBh[e8][k], &RBl[e8][k]);
        // re-zero K-padding cols 8..31 (clobbered by R2w alias each chunk)
        RBh[e8][k+8]=0;  RBh[e8][k+16]=0; RBh[e8][k+24]=0;
        RBl[e8][k+8]=0;  RBl[e8][k+16]=0; RBl[e8][k+24]=0;
      } else {
        int e8 = (tid-256) >> 3, u = tid & 7;
        int idx = t0 + e8;
        bool val = idx < deg;
        int eid = edge_slot[base + (val ? idx : 0)];
        float vx = edge_vectors[eid*3], vy = edge_vectors[eid*3+1], vz = edge_vectors[eid*3+2];
        float rn = sqrtf(vx*vx+vy*vy+vz*vz) + 1e-8f;
        float x = vx/rn, y = vy/rn, z = vz/rn;
        float sv;
        switch(u){
          case 0: sv = 1.f; break;
          case 1: sv = y; break;
          case 2: sv = z; break;
          case 3: sv = x; break;
          case 4: sv = 3.f*z*z-1.f; break;
          case 5: sv = x*z; break;
          case 6: sv = y*z; break;
          default: sv = x*y; break;
        }
        if (!val) sv = 0.f;
        split_store(sv, &SHh[u][e8], &SHl[u][e8]);
        if (u == 0){
          float s8 = val ? (x*x - y*y) : 0.f;
          split_store(s8, &SHh[8][e8], &SHl[8][e8]);
        }
      }
      __syncthreads();

      {
        bf16x8 Ah = ld8(&RBh[wm*16 + l15][lg*8]);
        bf16x8 Al = ld8(&RBl[wm*16 + l15][lg*8]);
        bf16x8 Bh = ld8(&W1h[wn2*16 + l15][lg*8]);
        bf16x8 Bl = ld8(&W1l[wn2*16 + l15][lg*8]);
        f32x4 z = {0.f,0.f,0.f,0.f};
        z = MFMA(Ah,Bl,z); z = MFMA(Al,Bh,z); z = MFMA(Ah,Bh,z);
        #pragma unroll
        for (int r=0;r<4;r++){
          int e8 = wm*16 + lg*4 + r;
          int c  = wn2*16 + l15;
          float v = silu_f(z[r] + b1v);
          split_store(v, &R1h[e8][c], &R1l[e8][c]);
        }
      }
      __syncthreads();

      #pragma unroll
      for (int et=0; et<2; et++){
        bf16x8 Bh0 = ld8(&R1h[et*16+l15][lg*8]);
        bf16x8 Bh1 = ld8(&R1h[et*16+l15][32+lg*8]);
        bf16x8 Bl0 = ld8(&R1l[et*16+l15][lg*8]);
        bf16x8 Bl1 = ld8(&R1l[et*16+l15][32+lg*8]);
        f32x4 z = {0.f,0.f,0.f,0.f};
        z = MFMA(WAl[0],Bh0,z); z = MFMA(WAl[1],Bh1,z);
        z = MFMA(WAh[0],Bl0,z); z = MFMA(WAh[1],Bl1,z);
        z = MFMA(WAh[0],Bh0,z); z = MFMA(WAh[1],Bh1,z);
        #pragma unroll
        for (int r=0;r<4;r++){
          float v = silu_f(z[r] + b2r[r]);
          split_store(v, &R2wh[w][lg*4+r][et*16+l15], &R2wl[w][lg*4+r][et*16+l15]);
        }
      }
      __asm__ volatile("s_waitcnt lgkmcnt(0)" ::: "memory");
      __builtin_amdgcn_sched_barrier(0);
      {
        bf16x8 Ah = ld8(&R2wh[w][l15][lg*8]);
        bf16x8 Al = ld8(&R2wl[w][l15][lg*8]);
        bf16x8 Bh = ld8(&SHh[l15][lg*8]);
        bf16x8 Bl = ld8(&SHl[l15][lg*8]);
        facc = MFMA(Ah,Bl,facc);
        facc = MFMA(Al,Bh,facc);
        facc = MFMA(Ah,Bh,facc);
      }
      __syncthreads();
    }

    if (l15 < 9){
      #pragma unroll
      for (int r=0;r<4;r++){
        int c = w*16 + lg*4 + r;
        size_t o = (size_t)l15*(N_ATOMS*128) + (size_t)a*128 + c;
        split_store(facc[r], &Fh[o], &Fl[o]);
      }
    }
  }
}

// ---------- fused node: agg GEMM + msg MLP + qkv (bf16 upd/Q/K/V^T out) ----------
__global__ __launch_bounds__(512) void node_kernel(
  const int* __restrict__ atomic_numbers, const float* __restrict__ atom_embed,
  const unsigned short* __restrict__ Fh, const unsigned short* __restrict__ Fl,
  const unsigned short* __restrict__ tpwT_h, const unsigned short* __restrict__ tpwT_l,
  const float* __restrict__ tp_b, const int* __restrict__ cursor,
  const unsigned short* __restrict__ w1T_h, const unsigned short* __restrict__ w1T_l,
  const float* __restrict__ msg_b1,
  const unsigned short* __restrict__ w2T_h, const unsigned short* __restrict__ w2T_l,
  const float* __restrict__ msg_b2,
  const unsigned short* __restrict__ awin_h, const unsigned short* __restrict__ awin_l,
  const float* __restrict__ attn_b_in,
  unsigned short* __restrict__ updh, unsigned short* __restrict__ updl,
  unsigned short* __restrict__ Qbf, unsigned short* __restrict__ Kbf,
  unsigned short* __restrict__ Vtb)
{
  const int a0 = blockIdx.x*16, tid = threadIdx.x;
  const int w = tid>>6, lane = tid&63, l15 = lane&15, lg = lane>>4;

  __shared__ unsigned short Ch[16][200], Cl[16][200];
  __shared__ unsigned short Hh[16][136], Hl[16][136];
  __shared__ unsigned short Uh[16][136], Ul[16][136];

  for (int i=tid; i<1024; i+=512){
    int a16=i>>6, k=i&63;
    float v = atom_embed[atomic_numbers[a0+a16]*64+k];
    split_store(v, &Ch[a16][k], &Cl[a16][k]);
  }

  // agg GEMM
  {
    f32x4 z = {0.f,0.f,0.f,0.f};
    for (int ch=0; ch<36; ch++){
      int k0=ch*32, j=k0>>7, c0=k0&127;
      size_t aoff = (size_t)j*(N_ATOMS*128) + (size_t)(a0+l15)*128 + c0 + lg*8;
      bf16x8 Ah=ld8(Fh+aoff), Al=ld8(Fl+aoff);
      size_t boff = (size_t)(w*16+l15)*1152 + k0 + lg*8;
      bf16x8 Bh=ld8(tpwT_h+boff), Bl=ld8(tpwT_l+boff);
      z = MFMA(Ah,Bl,z); z = MFMA(Al,Bh,z); z = MFMA(Ah,Bh,z);
    }
    int col = w*16+l15;
    float tb = tp_b[col];
    #pragma unroll
    for (int r=0;r<4;r++){
      int row = lg*4+r, arow = a0+row;
      float deg = (float)cursor[arow];
      float v = z[r] + tb*deg;
      split_store(v, &Ch[row][64+col], &Cl[row][64+col]);
    }
  }
  __syncthreads();

  // msg1
  {
    f32x4 z = {0.f,0.f,0.f,0.f};
    #pragma unroll
    for (int ch=0; ch<6; ch++){
      int k0=ch*32;
      bf16x8 Ah=ld8(&Ch[l15][k0+lg*8]), Al=ld8(&Cl[l15][k0+lg*8]);
      size_t boff=(size_t)(w*16+l15)*192 + k0 + lg*8;
      bf16x8 Bh=ld8(w1T_h+boff), Bl=ld8(w1T_l+boff);
      z = MFMA(Ah,Bl,z); z = MFMA(Al,Bh,z); z = MFMA(Ah,Bh,z);
    }
    int col = w*16+l15;
    float mb = msg_b1[col];
    #pragma unroll
    for (int r=0;r<4;r++){
      int row = lg*4+r;
      float v = silu_f(z[r]+mb);
      split_store(v, &Hh[row][col], &Hl[row][col]);
    }
  }
  __syncthreads();

  // msg2
  {
    f32x4 z = {0.f,0.f,0.f,0.f};
    #pragma unroll
    for (int ch=0; ch<4; ch++){
      int k0=ch*32;
      bf16x8 Ah=ld8(&Hh[l15][k0+lg*8]), Al=ld8(&Hl[l15][k0+lg*8]);
      size_t boff=(size_t)(w*16+l15)*128 + k0 + lg*8;
      bf16x8 Bh=ld8(w2T_h+boff), Bl=ld8(w2T_l+boff);
      z = MFMA(Ah,Bl,z); z = MFMA(Al,Bh,z); z = MFMA(Ah,Bh,z);
    }
    int col = w*16+l15;
    float mb = msg_b2[col];
    #pragma unroll
    for (int r=0;r<4;r++){
      int row = lg*4+r;
      float v = z[r]+mb;
      size_t o = (size_t)(a0+row)*128 + col;
      unsigned int hb = f2bf(v);
      updh[o] = (unsigned short)hb;
      float lo = v - __uint_as_float(hb<<16);
      updl[o] = (unsigned short)f2bf(lo);
      Uh[row][col] = (unsigned short)hb;
      Ul[row][col] = (unsigned short)f2bf(lo);
    }
  }
  __syncthreads();

  // qkv
  #pragma unroll
  for (int t3=0; t3<3; t3++){
    f32x4 z = {0.f,0.f,0.f,0.f};
    int col = (w*3+t3)*16 + l15;
    #pragma unroll
    for (int ch=0; ch<4; ch++){
      int k0=ch*32;
      bf16x8 Ah=ld8(&Uh[l15][k0+lg*8]), Al=ld8(&Ul[l15][k0+lg*8]);
      size_t boff=(size_t)col*128 + k0 + lg*8;
      bf16x8 Bh=ld8(awin_h+boff), Bl=ld8(awin_l+boff);
      z = MFMA(Ah,Bl,z); z = MFMA(Al,Bh,z); z = MFMA(Ah,Bh,z);
    }
    float ab = attn_b_in[col];
    int p = col>>7, hh = (col>>5)&3, dd = col&31;
    #pragma unroll
    for (int r=0;r<4;r++){
      int row = a0 + lg*4 + r;
      float v = z[r]+ab;
      if (p==0)      Qbf[(size_t)hh*131072 + (size_t)row*32 + dd] =
                       (unsigned short)f2bf(v*0.17677669529663687f);
      else if (p==1) Kbf[(size_t)hh*131072 + (size_t)row*32 + dd] = (unsigned short)f2bf(v);
      else           Vtb[(size_t)hh*131072 + (size_t)dd*4096 + row] = (unsigned short)f2bf(v);
    }
  }
}

// ---------- barrier-free MFMA flash attention (bf16 hi/lo att out) ----------
__global__ __launch_bounds__(512) void attn_kernel(
  const unsigned short* __restrict__ Qbf, const unsigned short* __restrict__ Kbf,
  const unsigned short* __restrict__ Vtb,
  unsigned short* __restrict__ atth, unsigned short* __restrict__ attl)
{
  const int tid = threadIdx.x;
  const int w = tid>>6, lane = tid&63, l15 = lane&15, lg = lane>>4;
  const int qjl = w>>2, ks = w&3;
  const int qj = blockIdx.x*2 + qjl;
  const int h = qj >> 8, qt = qj & 255;

  __shared__ unsigned short Ps[8][16][72];
  __shared__ float MBo[2][4][16][32];
  __shared__ float MBm[2][4][16];
  __shared__ float MBs[2][4][16];

  const unsigned short* Kb = Kbf + (size_t)h*131072;
  const unsigned short* Vb = Vtb + (size_t)h*131072;

  bf16x8 bQ = ld8(&Qbf[(size_t)h*131072 + (size_t)(qt*16+l15)*32 + lg*8]);

  float m = -3e38f, su = 0.f;
  f32x4 oacc[2] = {{0.f,0.f,0.f,0.f},{0.f,0.f,0.f,0.f}};

  for (int kt = ks*16; kt < ks*16 + 16; ++kt){
    const int k0 = kt*64;
    f32x4 s[4];
    #pragma unroll
    for (int n=0;n<4;n++){
      bf16x8 aK = ld8(&Kb[(size_t)(k0+n*16+l15)*32 + lg*8]);
      f32x4 z = {0.f,0.f,0.f,0.f};
      s[n] = MFMA(aK, bQ, z);
    }
    float tmax = s[0][0];
    #pragma unroll
    for (int n=0;n<4;n++)
      #pragma unroll
      for (int r=0;r<4;r++) tmax = fmaxf(tmax, s[n][r]);
    tmax = fmaxf(tmax, __shfl_xor(tmax,16,64));
    tmax = fmaxf(tmax, __shfl_xor(tmax,32,64));
    float mn = fmaxf(m, tmax);
    float csc = __expf(m - mn);
    m = mn;
    float psum = 0.f;
    unsigned int* prow = (unsigned int*)&Ps[w][l15][0];
    #pragma unroll
    for (int n=0;n<4;n++){
      float p0=__expf(s[n][0]-mn), p1=__expf(s[n][1]-mn);
      float p2=__expf(s[n][2]-mn), p3=__expf(s[n][3]-mn);
      psum += (p0+p1)+(p2+p3);
      prow[n*8+lg*2]   = f2bf(p0) | (f2bf(p1)<<16);
      prow[n*8+lg*2+1] = f2bf(p2) | (f2bf(p3)<<16);
    }
    psum += __shfl_xor(psum,16,64);
    psum += __shfl_xor(psum,32,64);
    su = su*csc + psum;
    float cr[4];
    #pragma unroll
    for (int r=0;r<4;r++) cr[r] = __shfl(csc, lg*4+r, 64);
    #pragma unroll
    for (int nd=0;nd<2;nd++)
      #pragma unroll
      for (int r=0;r<4;r++) oacc[nd][r] *= cr[r];
    __asm__ volatile("s_waitcnt lgkmcnt(0)" ::: "memory");
    #pragma unroll
    for (int kc=0;kc<2;kc++){
      bf16x8 aP = ld8(&Ps[w][l15][kc*32 + lg*8]);
      #pragma unroll
      for (int nd=0;nd<2;nd++){
        bf16x8 bV = ld8(&Vb[(size_t)(nd*16+l15)*4096 + k0 + kc*32 + lg*8]);
        oacc[nd] = MFMA(aP, bV, oacc[nd]);
      }
    }
  }

  if (lg==0){ MBm[qjl][ks][l15]=m; MBs[qjl][ks][l15]=su; }
  #pragma unroll
  for (int nd=0;nd<2;nd++)
    #pragma unroll
    for (int r=0;r<4;r++) MBo[qjl][ks][lg*4+r][nd*16+l15] = oacc[nd][r];
  __syncthreads();

  for (int idx = tid; idx < 1024; idx += 512){
    int qq = idx>>9, q = (idx>>5)&15, d = idx&31;
    float m0=MBm[qq][0][q], m1=MBm[qq][1][q], m2=MBm[qq][2][q], m3=MBm[qq][3][q];
    float mf = fmaxf(fmaxf(m0,m1), fmaxf(m2,m3));
    float c0=__expf(m0-mf), c1=__expf(m1-mf), c2=__expf(m2-mf), c3=__expf(m3-mf);
    float st = MBs[qq][0][q]*c0 + MBs[qq][1][q]*c1 + MBs[qq][2][q]*c2 + MBs[qq][3][q]*c3;
    float o  = MBo[qq][0][q][d]*c0 + MBo[qq][1][q][d]*c1 + MBo[qq][2][q][d]*c2 + MBo[qq][3][q][d]*c3;
    int qj2 = blockIdx.x*2 + qq;
    int hh = qj2>>8, qrow = (qj2&255)*16 + q;
    size_t off = (size_t)qrow*128 + hh*32 + d;
    split_store(o/st, &atth[off], &attl[off]);
  }
}

// ---------- MFMA epilogue: attn-out proj + gate + final proj; 16 atoms/block ----------
__global__ __launch_bounds__(512) void final_kernel(
  const unsigned short* __restrict__ atth, const unsigned short* __restrict__ attl,
  const unsigned short* __restrict__ updh, const unsigned short* __restrict__ updl,
  const unsigned short* __restrict__ awo_h, const unsigned short* __restrict__ awo_l,
  const float* __restrict__ attn_b_out,
  const unsigned short* __restrict__ gwT_h, const unsigned short* __restrict__ gwT_l,
  const float* __restrict__ gate_b,
  const unsigned short* __restrict__ owT_h, const unsigned short* __restrict__ owT_l,
  const float* __restrict__ out_b,
  float* __restrict__ out)
{
  const int a0 = blockIdx.x*16, tid = threadIdx.x;
  const int w = tid>>6, lane = tid&63, l15 = lane&15, lg = lane>>4;

  __shared__ unsigned short Th[16][136], Tl[16][136];

  const int col = w*16 + l15;

  f32x4 za = {0.f,0.f,0.f,0.f};
  f32x4 zg = {0.f,0.f,0.f,0.f};
  #pragma unroll
  for (int ch=0; ch<4; ch++){
    int k0=ch*32;
    size_t aoff = (size_t)(a0+l15)*128 + k0 + lg*8;
    bf16x8 Aah=ld8(atth+aoff), Aal=ld8(attl+aoff);
    bf16x8 Auh=ld8(updh+aoff), Aul=ld8(updl+aoff);
    size_t boff=(size_t)col*128 + k0 + lg*8;
    bf16x8 Bah=ld8(awo_h+boff), Bal=ld8(awo_l+boff);
    bf16x8 Bgh=ld8(gwT_h+boff), Bgl=ld8(gwT_l+boff);
    za = MFMA(Aah,Bal,za); za = MFMA(Aal,Bah,za); za = MFMA(Aah,Bah,za);
    zg = MFMA(Auh,Bgl,zg); zg = MFMA(Aul,Bgh,zg); zg = MFMA(Auh,Bgh,zg);
  }
  {
    float ab = attn_b_out[col], gb = gate_b[col];
    #pragma unroll
    for (int r=0;r<4;r++){
      int row = lg*4+r;
      size_t uo = (size_t)(a0+row)*128 + col;
      float uv = bf2f(updh[uo]) + bf2f(updl[uo]);
      float g = sigmoid_f(zg[r]+gb);
      float t = g*(za[r]+ab) + (1.f-g)*uv;
      split_store(t, &Th[row][col], &Tl[row][col]);
    }
  }
  __syncthreads();

  f32x4 zo = {0.f,0.f,0.f,0.f};
  #pragma unroll
  for (int ch=0; ch<4; ch++){
    int k0=ch*32;
    bf16x8 Ah=ld8(&Th[l15][k0+lg*8]), Al=ld8(&Tl[l15][k0+lg*8]);
    size_t boff=(size_t)col*128 + k0 + lg*8;
    bf16x8 Bh=ld8(owT_h+boff), Bl=ld8(owT_l+boff);
    zo = MFMA(Ah,Bl,zo); zo = MFMA(Al,Bh,zo); zo = MFMA(Ah,Bh,zo);
  }
  {
    float ob = out_b[col];
    #pragma unroll
    for (int r=0;r<4;r++){
      int row = lg*4+r;
      out[(size_t)(a0+row)*128 + col] = zo[r] + ob;
    }
  }
}

extern "C" void kernel_launch(void* const* d_in, const int* in_sizes, int n_in,
                              void* d_out, int out_size, void* d_ws, size_t ws_size,
                              hipStream_t stream){
  const int*   atomic_numbers = (const int*)  d_in[0];
  const int*   edge_index     = (const int*)  d_in[2];
  const float* edge_vectors   = (const float*)d_in[3];
  const float* edge_lengths   = (const float*)d_in[4];
  const float* atom_embed     = (const float*)d_in[5];
  const float* rad_w1 = (const float*)d_in[6];
  const float* rad_b1 = (const float*)d_in[7];
  const float* rad_w2 = (const float*)d_in[8];
  const float* rad_b2 = (const float*)d_in[9];
  const float* tp_w   = (const float*)d_in[10];
  const float* tp_b   = (const float*)d_in[11];
  const float* msg_w1 = (const float*)d_in[12];
  const float* msg_b1 = (const float*)d_in[13];
  const float* msg_w2 = (const float*)d_in[14];
  const float* msg_b2 = (const float*)d_in[15];
  const float* attn_w_in  = (const float*)d_in[16];
  const float* attn_b_in  = (const float*)d_in[17];
  const float* attn_w_out = (const float*)d_in[18];
  const float* attn_b_out = (const float*)d_in[19];
  const float* gate_w = (const float*)d_in[20];
  const float* gate_b = (const float*)d_in[21];
  const float* out_w  = (const float*)d_in[22];
  const float* out_b  = (const float*)d_in[23];

  // workspace layout (bytes)
  char* ws = (char*)d_ws;
  int* cursor    = (int*)(ws);                       // [0,16384)
  int* edge_slot = (int*)(ws + 16384);               // [16384,2113536)
  unsigned short* w2t_h  = (unsigned short*)(ws + 2113536);  // 16 KB
  unsigned short* w2t_l  = (unsigned short*)(ws + 2129920);  // 16 KB
  unsigned short* tpwT_h = (unsigned short*)(ws + 2146304);  // 288 KB
  unsigned short* tpwT_l = (unsigned short*)(ws + 2441216);  // 288 KB
  unsigned short* w1T_h  = (unsigned short*)(ws + 2736128);  // 48 KB
  unsigned short* w1T_l  = (unsigned short*)(ws + 2785280);  // 48 KB
  unsigned short* w2T_h  = (unsigned short*)(ws + 2834432);  // 32 KB
  unsigned short* w2T_l  = (unsigned short*)(ws + 2867200);  // 32 KB
  unsigned short* awin_h = (unsigned short*)(ws + 2899968);  // 96 KB
  unsigned short* awin_l = (unsigned short*)(ws + 2998272);  // 96 KB
  unsigned short* gwT_h  = (unsigned short*)(ws + 3096576);  // 32 KB
  unsigned short* gwT_l  = (unsigned short*)(ws + 3129344);  // 32 KB
  unsigned short* awo_h  = (unsigned short*)(ws + 3162112);  // 32 KB
  unsigned short* awo_l  = (unsigned short*)(ws + 3194880);  // 32 KB
  unsigned short* owT_h  = (unsigned short*)(ws + 3227648);  // 32 KB
  unsigned short* owT_l  = (unsigned short*)(ws + 3260416);  // 32 KB
  unsigned short* Fbf_h  = (unsigned short*)(ws + 3293184);  // 9.44 MB
  unsigned short* Fbf_l  = (unsigned short*)(ws + 12730368); // 9.44 MB
  unsigned short* atth   = (unsigned short*)(ws + 3293184);  // 1 MB (alias Fbf)
  unsigned short* attl   = (unsigned short*)(ws + 4341760);  // 1 MB
  unsigned short* updh   = (unsigned short*)(ws + 22167552); // 1 MB
  unsigned short* updl   = (unsigned short*)(ws + 23216128); // 1 MB
  unsigned short* Qbf    = (unsigned short*)(ws + 24264704); // 1 MB
  unsigned short* Kbf    = (unsigned short*)(ws + 25313280); // 1 MB
  unsigned short* Vtb    = (unsigned short*)(ws + 26361856); // 1 MB (end 27410432)

  prep_kernel<<<1152, 256, 0, stream>>>(attn_w_out, rad_w2, tp_w, msg_w1, msg_w2,
      attn_w_in, gate_w, out_w, cursor,
      w2t_h, w2t_l, tpwT_h, tpwT_l, w1T_h, w1T_l, w2T_h, w2T_l, awin_h, awin_l,
      gwT_h, gwT_l, awo_h, awo_l, owT_h, owT_l);
  bucket_kernel<<<(N_EDGES+255)/256, 256, 0, stream>>>(edge_index, cursor, edge_slot);
  edge_F_kernel<<<N_ATOMS/2, 512, 0, stream>>>(edge_vectors, edge_lengths,
      rad_w1, rad_b1, w2t_h, w2t_l, rad_b2, cursor, edge_slot, Fbf_h, Fbf_l);
  node_kernel<<<N_ATOMS/16, 512, 0, stream>>>(atomic_numbers, atom_embed,
      Fbf_h, Fbf_l, tpwT_h, tpwT_l, tp_b, cursor,
      w1T_h, w1T_l, msg_b1, w2T_h, w2T_l, msg_b2, awin_h, awin_l, attn_b_in,
      updh, updl, Qbf, Kbf, Vtb);
  attn_kernel<<<512, 512, 0, stream>>>(Qbf, Kbf, Vtb, atth, attl);
  final_kernel<<<N_ATOMS/16, 512, 0, stream>>>(atth, attl, updh, updl,
      awo_h, awo_l, attn_b_out, gwT_h, gwT_l, gate_b, owT_h, owT_l, out_b,
      (float*)d_out);
}

// Round 26
// 176.370 us; speedup vs baseline: 1.0071x; 1.0071x over previous
//
#include <hip/hip_runtime.h>
#include <math.h>

#define N_ATOMS 4096
#define N_EDGES 131072
#define PI6 0.52359877559829887f
#define CAP 128

typedef __attribute__((ext_vector_type(8))) short bf16x8;
typedef __attribute__((ext_vector_type(4))) float f32x4;

#define MFMA(A,B,C) __builtin_amdgcn_mfma_f32_16x16x32_bf16((A),(B),(C),0,0,0)

__device__ __forceinline__ float silu_f(float x){ return x / (1.f + __expf(-x)); }
__device__ __forceinline__ float sigmoid_f(float x){ return 1.f / (1.f + __expf(-x)); }
__device__ __forceinline__ unsigned int f2bf(float f){
  unsigned int u = __float_as_uint(f);
  return (u + 0x7FFFu + ((u>>16)&1u)) >> 16;
}
__device__ __forceinline__ float bf2f(unsigned short h){
  return __uint_as_float(((unsigned int)h)<<16);
}
__device__ __forceinline__ bf16x8 ld8(const unsigned short* p){
  union { unsigned int u[4]; bf16x8 v; } r;
  const unsigned int* q = (const unsigned int*)p;
  r.u[0]=q[0]; r.u[1]=q[1]; r.u[2]=q[2]; r.u[3]=q[3];
  return r.v;
}
__device__ __forceinline__ void split_store(float v, unsigned short* ph, unsigned short* pl){
  unsigned int hb = f2bf(v);
  *ph = (unsigned short)hb;
  *pl = (unsigned short)f2bf(v - __uint_as_float(hb<<16));
}

// ---------- prep: weight planes + zero bucket cursor ----------
__global__ __launch_bounds__(256) void prep_kernel(
  const float* __restrict__ attn_w_out, const float* __restrict__ rad_w2,
  const float* __restrict__ tp_w, const float* __restrict__ msg_w1,
  const float* __restrict__ msg_w2, const float* __restrict__ attn_w_in,
  const float* __restrict__ gate_w, const float* __restrict__ out_w,
  int* __restrict__ cursor,
  unsigned short* __restrict__ w2t_h, unsigned short* __restrict__ w2t_l,
  unsigned short* __restrict__ tpwT_h, unsigned short* __restrict__ tpwT_l,
  unsigned short* __restrict__ w1T_h, unsigned short* __restrict__ w1T_l,
  unsigned short* __restrict__ w2T_h, unsigned short* __restrict__ w2T_l,
  unsigned short* __restrict__ awin_h, unsigned short* __restrict__ awin_l,
  unsigned short* __restrict__ gwT_h, unsigned short* __restrict__ gwT_l,
  unsigned short* __restrict__ awo_h, unsigned short* __restrict__ awo_l,
  unsigned short* __restrict__ owT_h, unsigned short* __restrict__ owT_l)
{
  int idx = blockIdx.x*256 + threadIdx.x;
  if (idx < 4096) cursor[idx] = 0;
  if (idx < 8192){                        // w2t: rad_w2^T hi/lo [128][64]
    int j = idx; int k = j>>7, c = j&127;
    split_store(rad_w2[k*128+c], &w2t_h[c*64+k], &w2t_l[c*64+k]);
  } else if (idx < 155648){               // tpwT: [128 col][1152 k] reordered
    int j = idx - 8192; int col = j&127, kk = j>>7;
    int jj = kk>>7, c = kk&127;
    int r = (jj==0)? c : (jj<4 ? 128 + c*3 + (jj-1) : 512 + c*5 + (jj-4));
    split_store(tp_w[r*128+col], &tpwT_h[col*1152+kk], &tpwT_l[col*1152+kk]);
  } else if (idx < 180224){               // w1T: [128][192]
    int j = idx - 155648; int col = j&127, k = j>>7;
    split_store(msg_w1[k*128+col], &w1T_h[col*192+k], &w1T_l[col*192+k]);
  } else if (idx < 196608){               // w2T: [128][128]
    int j = idx - 180224; int col = j&127, k = j>>7;
    split_store(msg_w2[k*128+col], &w2T_h[col*128+k], &w2T_l[col*128+k]);
  } else if (idx < 245760){               // awin: attn_w_in [384][128] as-is
    int j = idx - 196608;
    split_store(attn_w_in[j], &awin_h[j], &awin_l[j]);
  } else if (idx < 262144){               // gwT: gate_w^T [col][k]
    int j = idx - 245760; int col = j&127, k = j>>7;
    split_store(gate_w[k*128+col], &gwT_h[col*128+k], &gwT_l[col*128+k]);
  } else if (idx < 278528){               // awo: attn_w_out as-is [o][k]
    int j = idx - 262144;
    split_store(attn_w_out[j], &awo_h[j], &awo_l[j]);
  } else if (idx < 294912){               // owT: out_w^T [col][k]
    int j = idx - 278528; int col = j&127, k = j>>7;
    split_store(out_w[k*128+col], &owT_h[col*128+k], &owT_l[col*128+k]);
  }
}

// ---------- bucket: per-atom edge lists via atomics ----------
__global__ __launch_bounds__(256) void bucket_kernel(
  const int* __restrict__ edge_index, int* __restrict__ cursor, int* __restrict__ edge_slot)
{
  int e = blockIdx.x*256 + threadIdx.x;
  if (e < N_EDGES){
    int d = edge_index[N_EDGES + e];
    int pos = atomicAdd(&cursor[d], 1);
    if (pos < CAP) edge_slot[d*CAP + pos] = e;
  }
}

// ---------- edge features: all-MFMA, 2 atoms/block, fused C+D ----------
__global__ __launch_bounds__(512) void edge_F_kernel(
  const float* __restrict__ edge_vectors, const float* __restrict__ edge_lengths,
  const float* __restrict__ rad_w1, const float* __restrict__ rad_b1,
  const unsigned short* __restrict__ w2t_h, const unsigned short* __restrict__ w2t_l,
  const float* __restrict__ rad_b2,
  const int* __restrict__ cursor, const int* __restrict__ edge_slot,
  unsigned short* __restrict__ Fh, unsigned short* __restrict__ Fl)
{
  const int tid = threadIdx.x;
  const int w = tid >> 6, lane = tid & 63;
  const int l15 = lane & 15, lg = lane >> 4;
  const int wm = w >> 2, wn2 = w & 3;

  __shared__ unsigned short W1h[64][36],  W1l[64][36];
  __shared__ unsigned short RBh[32][36],  RBl[32][36];
  __shared__ unsigned short SHh[16][36],  SHl[16][36];
  __shared__ unsigned short R1h[32][72],  R1l[32][72];
  __shared__ unsigned short R2wh[8][16][34], R2wl[8][16][34];

  bf16x8 WAh[2], WAl[2];
  {
    int c = w*16 + l15;
    WAh[0] = ld8(&w2t_h[c*64 + lg*8]);
    WAh[1] = ld8(&w2t_h[c*64 + 32 + lg*8]);
    WAl[0] = ld8(&w2t_l[c*64 + lg*8]);
    WAl[1] = ld8(&w2t_l[c*64 + 32 + lg*8]);
  }

  for (int i = tid; i < 2048; i += 512){
    int c = i >> 5, k = i & 31;
    float v = (k < 8) ? rad_w1[k*64 + c] : 0.f;
    split_store(v, &W1h[c][k], &W1l[c][k]);
  }
  for (int i = tid; i < 32*36; i += 512){ RBh[i/36][i%36]=0; RBl[i/36][i%36]=0; }
  for (int i = tid; i < 16*36; i += 512){ SHh[i/36][i%36]=0; SHl[i/36][i%36]=0; }

  const float b1v = rad_b1[wn2*16 + l15];
  float b2r[4];
  #pragma unroll
  for (int r=0;r<4;r++) b2r[r] = rad_b2[w*16 + lg*4 + r];

  __syncthreads();

  for (int aa = 0; aa < 2; ++aa){
    const int a = blockIdx.x*2 + aa;
    const int deg = min(cursor[a], CAP);
    const int base = a*CAP;
    f32x4 facc = {0.f,0.f,0.f,0.f};

    for (int t0 = 0; t0 < deg; t0 += 32){
      if (tid < 256){
        int e8 = tid >> 3, k = tid & 7;
        int idx = t0 + e8;
        int eid = edge_slot[base + (idx < deg ? idx : 0)];
        float d = edge_lengths[eid];
        float cut = 0.5f*(__cosf(d*PI6)+1.f)*(d<6.f?1.f:0.f);
        float rb = __sinf(d*((float)(k+1)*PI6))/d*cut;
        if (idx >= deg) rb = 0.f;
        split_store(rb, &RBh[e8][k], &RBl[e8][k]);
      } else {
        int e8 = (tid-256) >> 3, u = tid & 7;
        int idx = t0 + e8;
        bool val = idx < deg;
        int eid = edge_slot[base + (val ? idx : 0)];
        float vx = edge_vectors[eid*3], vy = edge_vectors[eid*3+1], vz = edge_vectors[eid*3+2];
        float rn = sqrtf(vx*vx+vy*vy+vz*vz) + 1e-8f;
        float x = vx/rn, y = vy/rn, z = vz/rn;
        float sv;
        switch(u){
          case 0: sv = 1.f; break;
          case 1: sv = y; break;
          case 2: sv = z; break;
          case 3: sv = x; break;
          case 4: sv = 3.f*z*z-1.f; break;
          case 5: sv = x*z; break;
          case 6: sv = y*z; break;
          default: sv = x*y; break;
        }
        if (!val) sv = 0.f;
        split_store(sv, &SHh[u][e8], &SHl[u][e8]);
        if (u == 0){
          float s8 = val ? (x*x - y*y) : 0.f;
          split_store(s8, &SHh[8][e8], &SHl[8][e8]);
        }
      }
      __syncthreads();

      {
        bf16x8 Ah = ld8(&RBh[wm*16 + l15][lg*8]);
        bf16x8 Al = ld8(&RBl[wm*16 + l15][lg*8]);
        bf16x8 Bh = ld8(&W1h[wn2*16 + l15][lg*8]);
        bf16x8 Bl = ld8(&W1l[wn2*16 + l15][lg*8]);
        f32x4 z = {0.f,0.f,0.f,0.f};
        z = MFMA(Ah,Bl,z); z = MFMA(Al,Bh,z); z = MFMA(Ah,Bh,z);
        #pragma unroll
        for (int r=0;r<4;r++){
          int e8 = wm*16 + lg*4 + r;
          int c  = wn2*16 + l15;
          float v = silu_f(z[r] + b1v);
          split_store(v, &R1h[e8][c], &R1l[e8][c]);
        }
      }
      __syncthreads();

      #pragma unroll
      for (int et=0; et<2; et++){
        bf16x8 Bh0 = ld8(&R1h[et*16+l15][lg*8]);
        bf16x8 Bh1 = ld8(&R1h[et*16+l15][32+lg*8]);
        bf16x8 Bl0 = ld8(&R1l[et*16+l15][lg*8]);
        bf16x8 Bl1 = ld8(&R1l[et*16+l15][32+lg*8]);
        f32x4 z = {0.f,0.f,0.f,0.f};
        z = MFMA(WAl[0],Bh0,z); z = MFMA(WAl[1],Bh1,z);
        z = MFMA(WAh[0],Bl0,z); z = MFMA(WAh[1],Bl1,z);
        z = MFMA(WAh[0],Bh0,z); z = MFMA(WAh[1],Bh1,z);
        #pragma unroll
        for (int r=0;r<4;r++){
          float v = silu_f(z[r] + b2r[r]);
          split_store(v, &R2wh[w][lg*4+r][et*16+l15], &R2wl[w][lg*4+r][et*16+l15]);
        }
      }
      __asm__ volatile("s_waitcnt lgkmcnt(0)" ::: "memory");
      __builtin_amdgcn_sched_barrier(0);
      {
        bf16x8 Ah = ld8(&R2wh[w][l15][lg*8]);
        bf16x8 Al = ld8(&R2wl[w][l15][lg*8]);
        bf16x8 Bh = ld8(&SHh[l15][lg*8]);
        bf16x8 Bl = ld8(&SHl[l15][lg*8]);
        facc = MFMA(Ah,Bl,facc);
        facc = MFMA(Al,Bh,facc);
        facc = MFMA(Ah,Bh,facc);
      }
      __syncthreads();
    }

    if (l15 < 9){
      #pragma unroll
      for (int r=0;r<4;r++){
        int c = w*16 + lg*4 + r;
        size_t o = (size_t)l15*(N_ATOMS*128) + (size_t)a*128 + c;
        split_store(facc[r], &Fh[o], &Fl[o]);
      }
    }
  }
}

// ---------- fused node: agg GEMM + msg MLP + qkv (bf16 upd/Q/K/V^T out) ----------
__global__ __launch_bounds__(512) void node_kernel(
  const int* __restrict__ atomic_numbers, const float* __restrict__ atom_embed,
  const unsigned short* __restrict__ Fh, const unsigned short* __restrict__ Fl,
  const unsigned short* __restrict__ tpwT_h, const unsigned short* __restrict__ tpwT_l,
  const float* __restrict__ tp_b, const int* __restrict__ cursor,
  const unsigned short* __restrict__ w1T_h, const unsigned short* __restrict__ w1T_l,
  const float* __restrict__ msg_b1,
  const unsigned short* __restrict__ w2T_h, const unsigned short* __restrict__ w2T_l,
  const float* __restrict__ msg_b2,
  const unsigned short* __restrict__ awin_h, const unsigned short* __restrict__ awin_l,
  const float* __restrict__ attn_b_in,
  unsigned short* __restrict__ updh, unsigned short* __restrict__ updl,
  unsigned short* __restrict__ Qbf, unsigned short* __restrict__ Kbf,
  unsigned short* __restrict__ Vtb)
{
  const int a0 = blockIdx.x*16, tid = threadIdx.x;
  const int w = tid>>6, lane = tid&63, l15 = lane&15, lg = lane>>4;

  __shared__ unsigned short Ch[16][200], Cl[16][200];
  __shared__ unsigned short Hh[16][136], Hl[16][136];
  __shared__ unsigned short Uh[16][136], Ul[16][136];

  for (int i=tid; i<1024; i+=512){
    int a16=i>>6, k=i&63;
    float v = atom_embed[atomic_numbers[a0+a16]*64+k];
    split_store(v, &Ch[a16][k], &Cl[a16][k]);
  }

  // agg GEMM
  {
    f32x4 z = {0.f,0.f,0.f,0.f};
    for (int ch=0; ch<36; ch++){
      int k0=ch*32, j=k0>>7, c0=k0&127;
      size_t aoff = (size_t)j*(N_ATOMS*128) + (size_t)(a0+l15)*128 + c0 + lg*8;
      bf16x8 Ah=ld8(Fh+aoff), Al=ld8(Fl+aoff);
      size_t boff = (size_t)(w*16+l15)*1152 + k0 + lg*8;
      bf16x8 Bh=ld8(tpwT_h+boff), Bl=ld8(tpwT_l+boff);
      z = MFMA(Ah,Bl,z); z = MFMA(Al,Bh,z); z = MFMA(Ah,Bh,z);
    }
    int col = w*16+l15;
    float tb = tp_b[col];
    #pragma unroll
    for (int r=0;r<4;r++){
      int row = lg*4+r, arow = a0+row;
      float deg = (float)cursor[arow];
      float v = z[r] + tb*deg;
      split_store(v, &Ch[row][64+col], &Cl[row][64+col]);
    }
  }
  __syncthreads();

  // msg1
  {
    f32x4 z = {0.f,0.f,0.f,0.f};
    #pragma unroll
    for (int ch=0; ch<6; ch++){
      int k0=ch*32;
      bf16x8 Ah=ld8(&Ch[l15][k0+lg*8]), Al=ld8(&Cl[l15][k0+lg*8]);
      size_t boff=(size_t)(w*16+l15)*192 + k0 + lg*8;
      bf16x8 Bh=ld8(w1T_h+boff), Bl=ld8(w1T_l+boff);
      z = MFMA(Ah,Bl,z); z = MFMA(Al,Bh,z); z = MFMA(Ah,Bh,z);
    }
    int col = w*16+l15;
    float mb = msg_b1[col];
    #pragma unroll
    for (int r=0;r<4;r++){
      int row = lg*4+r;
      float v = silu_f(z[r]+mb);
      split_store(v, &Hh[row][col], &Hl[row][col]);
    }
  }
  __syncthreads();

  // msg2
  {
    f32x4 z = {0.f,0.f,0.f,0.f};
    #pragma unroll
    for (int ch=0; ch<4; ch++){
      int k0=ch*32;
      bf16x8 Ah=ld8(&Hh[l15][k0+lg*8]), Al=ld8(&Hl[l15][k0+lg*8]);
      size_t boff=(size_t)(w*16+l15)*128 + k0 + lg*8;
      bf16x8 Bh=ld8(w2T_h+boff), Bl=ld8(w2T_l+boff);
      z = MFMA(Ah,Bl,z); z = MFMA(Al,Bh,z); z = MFMA(Ah,Bh,z);
    }
    int col = w*16+l15;
    float mb = msg_b2[col];
    #pragma unroll
    for (int r=0;r<4;r++){
      int row = lg*4+r;
      float v = z[r]+mb;
      size_t o = (size_t)(a0+row)*128 + col;
      unsigned int hb = f2bf(v);
      updh[o] = (unsigned short)hb;
      float lo = v - __uint_as_float(hb<<16);
      updl[o] = (unsigned short)f2bf(lo);
      Uh[row][col] = (unsigned short)hb;
      Ul[row][col] = (unsigned short)f2bf(lo);
    }
  }
  __syncthreads();

  // qkv
  #pragma unroll
  for (int t3=0; t3<3; t3++){
    f32x4 z = {0.f,0.f,0.f,0.f};
    int col = (w*3+t3)*16 + l15;
    #pragma unroll
    for (int ch=0; ch<4; ch++){
      int k0=ch*32;
      bf16x8 Ah=ld8(&Uh[l15][k0+lg*8]), Al=ld8(&Ul[l15][k0+lg*8]);
      size_t boff=(size_t)col*128 + k0 + lg*8;
      bf16x8 Bh=ld8(awin_h+boff), Bl=ld8(awin_l+boff);
      z = MFMA(Ah,Bl,z); z = MFMA(Al,Bh,z); z = MFMA(Ah,Bh,z);
    }
    float ab = attn_b_in[col];
    int p = col>>7, hh = (col>>5)&3, dd = col&31;
    #pragma unroll
    for (int r=0;r<4;r++){
      int row = a0 + lg*4 + r;
      float v = z[r]+ab;
      if (p==0)      Qbf[(size_t)hh*131072 + (size_t)row*32 + dd] =
                       (unsigned short)f2bf(v*0.17677669529663687f);
      else if (p==1) Kbf[(size_t)hh*131072 + (size_t)row*32 + dd] = (unsigned short)f2bf(v);
      else           Vtb[(size_t)hh*131072 + (size_t)dd*4096 + row] = (unsigned short)f2bf(v);
    }
  }
}

// ---------- barrier-free MFMA flash attention (bf16 hi/lo att out) ----------
__global__ __launch_bounds__(512) void attn_kernel(
  const unsigned short* __restrict__ Qbf, const unsigned short* __restrict__ Kbf,
  const unsigned short* __restrict__ Vtb,
  unsigned short* __restrict__ atth, unsigned short* __restrict__ attl)
{
  const int tid = threadIdx.x;
  const int w = tid>>6, lane = tid&63, l15 = lane&15, lg = lane>>4;
  const int qjl = w>>2, ks = w&3;
  const int qj = blockIdx.x*2 + qjl;
  const int h = qj >> 8, qt = qj & 255;

  __shared__ unsigned short Ps[8][16][72];
  __shared__ float MBo[2][4][16][32];
  __shared__ float MBm[2][4][16];
  __shared__ float MBs[2][4][16];

  const unsigned short* Kb = Kbf + (size_t)h*131072;
  const unsigned short* Vb = Vtb + (size_t)h*131072;

  bf16x8 bQ = ld8(&Qbf[(size_t)h*131072 + (size_t)(qt*16+l15)*32 + lg*8]);

  float m = -3e38f, su = 0.f;
  f32x4 oacc[2] = {{0.f,0.f,0.f,0.f},{0.f,0.f,0.f,0.f}};

  for (int kt = ks*16; kt < ks*16 + 16; ++kt){
    const int k0 = kt*64;
    f32x4 s[4];
    #pragma unroll
    for (int n=0;n<4;n++){
      bf16x8 aK = ld8(&Kb[(size_t)(k0+n*16+l15)*32 + lg*8]);
      f32x4 z = {0.f,0.f,0.f,0.f};
      s[n] = MFMA(aK, bQ, z);
    }
    float tmax = s[0][0];
    #pragma unroll
    for (int n=0;n<4;n++)
      #pragma unroll
      for (int r=0;r<4;r++) tmax = fmaxf(tmax, s[n][r]);
    tmax = fmaxf(tmax, __shfl_xor(tmax,16,64));
    tmax = fmaxf(tmax, __shfl_xor(tmax,32,64));
    float mn = fmaxf(m, tmax);
    float csc = __expf(m - mn);
    m = mn;
    float psum = 0.f;
    unsigned int* prow = (unsigned int*)&Ps[w][l15][0];
    #pragma unroll
    for (int n=0;n<4;n++){
      float p0=__expf(s[n][0]-mn), p1=__expf(s[n][1]-mn);
      float p2=__expf(s[n][2]-mn), p3=__expf(s[n][3]-mn);
      psum += (p0+p1)+(p2+p3);
      prow[n*8+lg*2]   = f2bf(p0) | (f2bf(p1)<<16);
      prow[n*8+lg*2+1] = f2bf(p2) | (f2bf(p3)<<16);
    }
    psum += __shfl_xor(psum,16,64);
    psum += __shfl_xor(psum,32,64);
    su = su*csc + psum;
    float cr[4];
    #pragma unroll
    for (int r=0;r<4;r++) cr[r] = __shfl(csc, lg*4+r, 64);
    #pragma unroll
    for (int nd=0;nd<2;nd++)
      #pragma unroll
      for (int r=0;r<4;r++) oacc[nd][r] *= cr[r];
    __asm__ volatile("s_waitcnt lgkmcnt(0)" ::: "memory");
    #pragma unroll
    for (int kc=0;kc<2;kc++){
      bf16x8 aP = ld8(&Ps[w][l15][kc*32 + lg*8]);
      #pragma unroll
      for (int nd=0;nd<2;nd++){
        bf16x8 bV = ld8(&Vb[(size_t)(nd*16+l15)*4096 + k0 + kc*32 + lg*8]);
        oacc[nd] = MFMA(aP, bV, oacc[nd]);
      }
    }
  }

  if (lg==0){ MBm[qjl][ks][l15]=m; MBs[qjl][ks][l15]=su; }
  #pragma unroll
  for (int nd=0;nd<2;nd++)
    #pragma unroll
    for (int r=0;r<4;r++) MBo[qjl][ks][lg*4+r][nd*16+l15] = oacc[nd][r];
  __syncthreads();

  for (int idx = tid; idx < 1024; idx += 512){
    int qq = idx>>9, q = (idx>>5)&15, d = idx&31;
    float m0=MBm[qq][0][q], m1=MBm[qq][1][q], m2=MBm[qq][2][q], m3=MBm[qq][3][q];
    float mf = fmaxf(fmaxf(m0,m1), fmaxf(m2,m3));
    float c0=__expf(m0-mf), c1=__expf(m1-mf), c2=__expf(m2-mf), c3=__expf(m3-mf);
    float st = MBs[qq][0][q]*c0 + MBs[qq][1][q]*c1 + MBs[qq][2][q]*c2 + MBs[qq][3][q]*c3;
    float o  = MBo[qq][0][q][d]*c0 + MBo[qq][1][q][d]*c1 + MBo[qq][2][q][d]*c2 + MBo[qq][3][q][d]*c3;
    int qj2 = blockIdx.x*2 + qq;
    int hh = qj2>>8, qrow = (qj2&255)*16 + q;
    size_t off = (size_t)qrow*128 + hh*32 + d;
    split_store(o/st, &atth[off], &attl[off]);
  }
}

// ---------- MFMA epilogue: attn-out proj + gate + final proj; 16 atoms/block ----------
__global__ __launch_bounds__(512) void final_kernel(
  const unsigned short* __restrict__ atth, const unsigned short* __restrict__ attl,
  const unsigned short* __restrict__ updh, const unsigned short* __restrict__ updl,
  const unsigned short* __restrict__ awo_h, const unsigned short* __restrict__ awo_l,
  const float* __restrict__ attn_b_out,
  const unsigned short* __restrict__ gwT_h, const unsigned short* __restrict__ gwT_l,
  const float* __restrict__ gate_b,
  const unsigned short* __restrict__ owT_h, const unsigned short* __restrict__ owT_l,
  const float* __restrict__ out_b,
  float* __restrict__ out)
{
  const int a0 = blockIdx.x*16, tid = threadIdx.x;
  const int w = tid>>6, lane = tid&63, l15 = lane&15, lg = lane>>4;

  __shared__ unsigned short Th[16][136], Tl[16][136];

  const int col = w*16 + l15;

  f32x4 za = {0.f,0.f,0.f,0.f};
  f32x4 zg = {0.f,0.f,0.f,0.f};
  #pragma unroll
  for (int ch=0; ch<4; ch++){
    int k0=ch*32;
    size_t aoff = (size_t)(a0+l15)*128 + k0 + lg*8;
    bf16x8 Aah=ld8(atth+aoff), Aal=ld8(attl+aoff);
    bf16x8 Auh=ld8(updh+aoff), Aul=ld8(updl+aoff);
    size_t boff=(size_t)col*128 + k0 + lg*8;
    bf16x8 Bah=ld8(awo_h+boff), Bal=ld8(awo_l+boff);
    bf16x8 Bgh=ld8(gwT_h+boff), Bgl=ld8(gwT_l+boff);
    za = MFMA(Aah,Bal,za); za = MFMA(Aal,Bah,za); za = MFMA(Aah,Bah,za);
    zg = MFMA(Auh,Bgl,zg); zg = MFMA(Aul,Bgh,zg); zg = MFMA(Auh,Bgh,zg);
  }
  {
    float ab = attn_b_out[col], gb = gate_b[col];
    #pragma unroll
    for (int r=0;r<4;r++){
      int row = lg*4+r;
      size_t uo = (size_t)(a0+row)*128 + col;
      float uv = bf2f(updh[uo]) + bf2f(updl[uo]);
      float g = sigmoid_f(zg[r]+gb);
      float t = g*(za[r]+ab) + (1.f-g)*uv;
      split_store(t, &Th[row][col], &Tl[row][col]);
    }
  }
  __syncthreads();

  f32x4 zo = {0.f,0.f,0.f,0.f};
  #pragma unroll
  for (int ch=0; ch<4; ch++){
    int k0=ch*32;
    bf16x8 Ah=ld8(&Th[l15][k0+lg*8]), Al=ld8(&Tl[l15][k0+lg*8]);
    size_t boff=(size_t)col*128 + k0 + lg*8;
    bf16x8 Bh=ld8(owT_h+boff), Bl=ld8(owT_l+boff);
    zo = MFMA(Ah,Bl,zo); zo = MFMA(Al,Bh,zo); zo = MFMA(Ah,Bh,zo);
  }
  {
    float ob = out_b[col];
    #pragma unroll
    for (int r=0;r<4;r++){
      int row = lg*4+r;
      out[(size_t)(a0+row)*128 + col] = zo[r] + ob;
    }
  }
}

extern "C" void kernel_launch(void* const* d_in, const int* in_sizes, int n_in,
                              void* d_out, int out_size, void* d_ws, size_t ws_size,
                              hipStream_t stream){
  const int*   atomic_numbers = (const int*)  d_in[0];
  const int*   edge_index     = (const int*)  d_in[2];
  const float* edge_vectors   = (const float*)d_in[3];
  const float* edge_lengths   = (const float*)d_in[4];
  const float* atom_embed     = (const float*)d_in[5];
  const float* rad_w1 = (const float*)d_in[6];
  const float* rad_b1 = (const float*)d_in[7];
  const float* rad_w2 = (const float*)d_in[8];
  const float* rad_b2 = (const float*)d_in[9];
  const float* tp_w   = (const float*)d_in[10];
  const float* tp_b   = (const float*)d_in[11];
  const float* msg_w1 = (const float*)d_in[12];
  const float* msg_b1 = (const float*)d_in[13];
  const float* msg_w2 = (const float*)d_in[14];
  const float* msg_b2 = (const float*)d_in[15];
  const float* attn_w_in  = (const float*)d_in[16];
  const float* attn_b_in  = (const float*)d_in[17];
  const float* attn_w_out = (const float*)d_in[18];
  const float* attn_b_out = (const float*)d_in[19];
  const float* gate_w = (const float*)d_in[20];
  const float* gate_b = (const float*)d_in[21];
  const float* out_w  = (const float*)d_in[22];
  const float* out_b  = (const float*)d_in[23];

  // workspace layout (bytes)
  char* ws = (char*)d_ws;
  int* cursor    = (int*)(ws);                       // [0,16384)
  int* edge_slot = (int*)(ws + 16384);               // [16384,2113536)
  unsigned short* w2t_h  = (unsigned short*)(ws + 2113536);  // 16 KB
  unsigned short* w2t_l  = (unsigned short*)(ws + 2129920);  // 16 KB
  unsigned short* tpwT_h = (unsigned short*)(ws + 2146304);  // 288 KB
  unsigned short* tpwT_l = (unsigned short*)(ws + 2441216);  // 288 KB
  unsigned short* w1T_h  = (unsigned short*)(ws + 2736128);  // 48 KB
  unsigned short* w1T_l  = (unsigned short*)(ws + 2785280);  // 48 KB
  unsigned short* w2T_h  = (unsigned short*)(ws + 2834432);  // 32 KB
  unsigned short* w2T_l  = (unsigned short*)(ws + 2867200);  // 32 KB
  unsigned short* awin_h = (unsigned short*)(ws + 2899968);  // 96 KB
  unsigned short* awin_l = (unsigned short*)(ws + 2998272);  // 96 KB
  unsigned short* gwT_h  = (unsigned short*)(ws + 3096576);  // 32 KB
  unsigned short* gwT_l  = (unsigned short*)(ws + 3129344);  // 32 KB
  unsigned short* awo_h  = (unsigned short*)(ws + 3162112);  // 32 KB
  unsigned short* awo_l  = (unsigned short*)(ws + 3194880);  // 32 KB
  unsigned short* owT_h  = (unsigned short*)(ws + 3227648);  // 32 KB
  unsigned short* owT_l  = (unsigned short*)(ws + 3260416);  // 32 KB
  unsigned short* Fbf_h  = (unsigned short*)(ws + 3293184);  // 9.44 MB
  unsigned short* Fbf_l  = (unsigned short*)(ws + 12730368); // 9.44 MB
  unsigned short* atth   = (unsigned short*)(ws + 3293184);  // 1 MB (alias Fbf)
  unsigned short* attl   = (unsigned short*)(ws + 4341760);  // 1 MB
  unsigned short* updh   = (unsigned short*)(ws + 22167552); // 1 MB
  unsigned short* updl   = (unsigned short*)(ws + 23216128); // 1 MB
  unsigned short* Qbf    = (unsigned short*)(ws + 24264704); // 1 MB
  unsigned short* Kbf    = (unsigned short*)(ws + 25313280); // 1 MB
  unsigned short* Vtb    = (unsigned short*)(ws + 26361856); // 1 MB (end 27410432)

  prep_kernel<<<1152, 256, 0, stream>>>(attn_w_out, rad_w2, tp_w, msg_w1, msg_w2,
      attn_w_in, gate_w, out_w, cursor,
      w2t_h, w2t_l, tpwT_h, tpwT_l, w1T_h, w1T_l, w2T_h, w2T_l, awin_h, awin_l,
      gwT_h, gwT_l, awo_h, awo_l, owT_h, owT_l);
  bucket_kernel<<<(N_EDGES+255)/256, 256, 0, stream>>>(edge_index, cursor, edge_slot);
  edge_F_kernel<<<N_ATOMS/2, 512, 0, stream>>>(edge_vectors, edge_lengths,
      rad_w1, rad_b1, w2t_h, w2t_l, rad_b2, cursor, edge_slot, Fbf_h, Fbf_l);
  node_kernel<<<N_ATOMS/16, 512, 0, stream>>>(atomic_numbers, atom_embed,
      Fbf_h, Fbf_l, tpwT_h, tpwT_l, tp_b, cursor,
      w1T_h, w1T_l, msg_b1, w2T_h, w2T_l, msg_b2, awin_h, awin_l, attn_b_in,
      updh, updl, Qbf, Kbf, Vtb);
  attn_kernel<<<512, 512, 0, stream>>>(Qbf, Kbf, Vtb, atth, attl);
  final_kernel<<<N_ATOMS/16, 512, 0, stream>>>(atth, attl, updh, updl,
      awo_h, awo_l, attn_b_out, gwT_h, gwT_l, gate_b, owT_h, owT_l, out_b,
      (float*)d_out);
}